// Round 1
// baseline (737.648 us; speedup 1.0000x reference)
//
#include <hip/hip_runtime.h>
#include <cstdint>
#include <cstddef>

// ArcFace: e=l2norm(emb) [1024,512]; w=l2norm(weight) [100000,512];
// cos = clip(e@w^T, -1, 1); at (r, labels[r]): cos(theta+0.5); out = 30*logits.
// Margin closed form: cos(theta+M) = cosM*c - sinM*sqrt(1-c^2)  (theta in [0,pi]).
//
// This version FUSES the W normalization into the GEMM:
//   cos = (e_hat . w) * 1/max(||w||,eps)   (normalization is a per-row linear scale)
// W is read as raw f32 via global_load_lds; fragments are converted f32->bf16 in
// registers; sum(w^2) is accumulated from the staged f32 tiles on the fly.
// Grid is 1D with a bijective XCD swizzle (784 panels = 8*98) so the 8 M-blocks
// sharing a W panel land on the same XCD's L2.

constexpr int N_ROWS = 1024;
constexpr int DIM    = 512;
constexpr int C_CLS  = 100000;
constexpr int NPANEL = 784;          // 784*128 = 100352 padded cols; 784 = 8*98 (bijective swizzle)
constexpr int MTILES = 8;            // 1024/128

#define COS_M 0.87758256189037271612f
#define SIN_M 0.47942553860420300027f

typedef __attribute__((ext_vector_type(8))) __bf16 bf16x8;
typedef __attribute__((ext_vector_type(4))) float  floatx4;

__device__ inline unsigned short f2bf(float f) {
    unsigned int u = __float_as_uint(f);
    u += 0x7FFFu + ((u >> 16) & 1u);   // round-to-nearest-even
    return (unsigned short)(u >> 16);
}

__device__ inline float wave_reduce_sum(float v) {
    v += __shfl_xor(v, 32, 64);
    v += __shfl_xor(v, 16, 64);
    v += __shfl_xor(v, 8, 64);
    v += __shfl_xor(v, 4, 64);
    v += __shfl_xor(v, 2, 64);
    v += __shfl_xor(v, 1, 64);
    return v;
}

__device__ inline void async16(const void* g, void* l) {
    __builtin_amdgcn_global_load_lds(
        (const __attribute__((address_space(1))) void*)g,
        (__attribute__((address_space(3))) void*)l,
        16, 0, 0);
}

// One wave per row: l2-normalize float row -> bf16 row (A side only now).
__global__ __launch_bounds__(256) void normalize_rows(
    const float* __restrict__ in, unsigned short* __restrict__ out, int rows) {
    int wave = (int)((blockIdx.x * 256u + threadIdx.x) >> 6);
    int lane = threadIdx.x & 63;
    if (wave >= rows) return;

    const float4* rp = (const float4*)(in + (size_t)wave * DIM);
    float4 x0 = rp[lane];        // cols 4*lane .. +4
    float4 x1 = rp[64 + lane];   // cols 256 + 4*lane .. +4
    float s = x0.x*x0.x + x0.y*x0.y + x0.z*x0.z + x0.w*x0.w
            + x1.x*x1.x + x1.y*x1.y + x1.z*x1.z + x1.w*x1.w;
    s = wave_reduce_sum(s);
    float inv = 1.0f / fmaxf(sqrtf(s), 1e-12f);
    unsigned short* orow = out + (size_t)wave * DIM;
    ushort4 o0, o1;
    o0.x = f2bf(x0.x * inv); o0.y = f2bf(x0.y * inv);
    o0.z = f2bf(x0.z * inv); o0.w = f2bf(x0.w * inv);
    o1.x = f2bf(x1.x * inv); o1.y = f2bf(x1.y * inv);
    o1.z = f2bf(x1.z * inv); o1.w = f2bf(x1.w * inv);
    ((ushort4*)orow)[lane]      = o0;
    ((ushort4*)orow)[64 + lane] = o1;
}

// 128x128 tile GEMM, A bf16 (pre-normalized), W raw f32 (normalized via post-scale).
__global__ __launch_bounds__(256) void arcface_gemm(
    const unsigned short* __restrict__ A,
    const float* __restrict__ Wf,
    const int* __restrict__ labels,
    float* __restrict__ out) {
    __shared__ unsigned short As[128 * 32];  // [m][k] bf16, 8 KiB, XOR-swizzled slots (slot^row&3)
    __shared__ float          Bs[128 * 32];  // [n][k] f32, 16 KiB, XOR-swizzled slots (slot^row&7)
    __shared__ int   labs[128];
    __shared__ float winv[128];

    const int tid  = threadIdx.x;
    const int lane = tid & 63;
    const int wv   = tid >> 6;       // 0..3
    const int wr   = wv >> 1;        // wave row quadrant (64 rows)
    const int wc   = wv & 1;         // wave col quadrant (64 cols)

    // Bijective XCD swizzle: bid%8 -> XCD (round-robin). Give each XCD 98
    // contiguous panels; the 8 M-blocks of a panel sit 8 apart in bid -> same XCD,
    // dispatched within a 64-bid window (near-simultaneous, panel fetched once).
    const int bid   = blockIdx.x;
    const int xcd   = bid & 7;
    const int s     = bid >> 3;                 // 0..783
    const int panel = xcd * (NPANEL / 8) + (s >> 3);
    const int mtile = s & 7;
    const int mbase = mtile * 128;
    const int nbase = panel * 128;

    if (tid < 128) labs[tid] = labels[mbase + tid];

    // ---- staging coordinates (linear LDS dest; XOR-swizzled global source) ----
    // A: 512 chunks of 16B; c = tid + 256*q (q=0,1); row=c>>2, slot=c&3
    const int arow0  = tid >> 2;                       // rows 0..63
    const int aslot0 = (tid & 3) ^ (arow0 & 3);
    const int arow1  = arow0 + 64;                     // rows 64..127
    const int aslot1 = (tid & 3) ^ (arow1 & 3);
    // B: 1024 chunks of 16B; c = tid + 256*q (q=0..3); row=c>>3, slot=c&7
    size_t bsrc[4];
    #pragma unroll
    for (int q = 0; q < 4; q++) {
        int c    = tid + 256 * q;
        int row  = c >> 3;
        int slot = (c & 7) ^ (row & 7);
        int grow = nbase + row;
        if (grow > C_CLS - 1) grow = C_CLS - 1;        // clamp padded rows (no OOB read)
        bsrc[q] = (size_t)grow * DIM + (size_t)(slot * 4);
    }

    const unsigned short* Ag = A + (size_t)mbase * DIM;

    const int kq   = (lane >> 4) * 8;   // k offset of this lane's fragment
    const int mrow = lane & 15;

    // ---- fragment LDS indices (k0-invariant, hoisted) ----
    int aidx[4];
    #pragma unroll
    for (int i = 0; i < 4; i++) {
        int row = wr * 64 + i * 16 + mrow;
        aidx[i] = row * 32 + (((kq >> 3) ^ (row & 3)) << 3);      // ushort index
    }
    int bidx0[4], bidx1[4];
    #pragma unroll
    for (int j = 0; j < 4; j++) {
        int row  = wc * 64 + j * 16 + mrow;
        bidx0[j] = row * 32 + ((((kq >> 2)    ) ^ (row & 7)) << 2); // float index
        bidx1[j] = row * 32 + ((((kq >> 2) + 1) ^ (row & 7)) << 2);
    }

    floatx4 acc[4][4];
    #pragma unroll
    for (int i = 0; i < 4; i++)
        #pragma unroll
        for (int j = 0; j < 4; j++)
            acc[i][j] = (floatx4){0.f, 0.f, 0.f, 0.f};
    float ssq[2] = {0.f, 0.f};   // this wave's sum(w^2) partials (j = wr*2 + jj)

    for (int k0 = 0; k0 < DIM; k0 += 32) {
        async16(Ag + (size_t)arow0 * DIM + k0 + aslot0 * 8, &As[tid * 8]);
        async16(Ag + (size_t)arow1 * DIM + k0 + aslot1 * 8, &As[2048 + tid * 8]);
        #pragma unroll
        for (int q = 0; q < 4; q++)
            async16(Wf + bsrc[q] + k0, &Bs[(tid + 256 * q) * 4]);
        __syncthreads();

        bf16x8 af[4], bfr[4];
        #pragma unroll
        for (int i = 0; i < 4; i++)
            af[i] = *(const bf16x8*)&As[aidx[i]];
        #pragma unroll
        for (int j = 0; j < 4; j++) {
            float4 lo = *(const float4*)&Bs[bidx0[j]];
            float4 hi = *(const float4*)&Bs[bidx1[j]];
            bf16x8 b;
            b[0] = (__bf16)lo.x; b[1] = (__bf16)lo.y;
            b[2] = (__bf16)lo.z; b[3] = (__bf16)lo.w;
            b[4] = (__bf16)hi.x; b[5] = (__bf16)hi.y;
            b[6] = (__bf16)hi.z; b[7] = (__bf16)hi.w;
            bfr[j] = b;
            if (wr == (j >> 1)) {   // wave-uniform: wr0 owns j=0,1; wr1 owns j=2,3
                float t = ssq[j & 1];
                t = fmaf(lo.x, lo.x, t); t = fmaf(lo.y, lo.y, t);
                t = fmaf(lo.z, lo.z, t); t = fmaf(lo.w, lo.w, t);
                t = fmaf(hi.x, hi.x, t); t = fmaf(hi.y, hi.y, t);
                t = fmaf(hi.z, hi.z, t); t = fmaf(hi.w, hi.w, t);
                ssq[j & 1] = t;
            }
        }
        #pragma unroll
        for (int i = 0; i < 4; i++)
            #pragma unroll
            for (int j = 0; j < 4; j++)
                acc[i][j] = __builtin_amdgcn_mfma_f32_16x16x32_bf16(
                    af[i], bfr[j], acc[i][j], 0, 0, 0);
        __syncthreads();
    }

    // ---- finish ||w|| per tile row: reduce the 4 kq lane-groups, write winv ----
    #pragma unroll
    for (int jj = 0; jj < 2; jj++) {
        float v = ssq[jj];
        v += __shfl_xor(v, 16, 64);
        v += __shfl_xor(v, 32, 64);
        if (lane < 16)
            winv[wc * 64 + wr * 32 + jj * 16 + lane] = 1.0f / fmaxf(sqrtf(v), 1e-12f);
    }
    __syncthreads();

    float wnv[4];
    #pragma unroll
    for (int j = 0; j < 4; j++) wnv[j] = winv[wc * 64 + j * 16 + mrow];

    // Epilogue: C/D layout col = lane&15, row = (lane>>4)*4 + reg
    const int col0 = nbase + wc * 64 + mrow;
    #pragma unroll
    for (int i = 0; i < 4; i++) {
        const int rbase = wr * 64 + i * 16 + (lane >> 4) * 4;
        #pragma unroll
        for (int r = 0; r < 4; r++) {
            const int row  = rbase + r;
            const int grow = mbase + row;
            const int lab  = labs[row];
            float* orow = out + (size_t)grow * C_CLS;
            #pragma unroll
            for (int j = 0; j < 4; j++) {
                const int gc = col0 + j * 16;
                if (gc < C_CLS) {
                    float c = acc[i][j][r] * wnv[j];
                    c = fminf(1.0f, fmaxf(-1.0f, c));
                    float v = c;
                    if (gc == lab) {
                        v = COS_M * c - SIN_M * sqrtf(fmaxf(0.0f, 1.0f - c * c));
                    }
                    orow[gc] = 30.0f * v;
                }
            }
        }
    }
}

extern "C" void kernel_launch(void* const* d_in, const int* in_sizes, int n_in,
                              void* d_out, int out_size, void* d_ws, size_t ws_size,
                              hipStream_t stream) {
    const float* emb    = (const float*)d_in[0];
    const float* wgt    = (const float*)d_in[1];
    const int*   labels = (const int*)d_in[2];
    float*       out    = (float*)d_out;

    unsigned short* An = (unsigned short*)d_ws;   // 1024*512 bf16 = 1 MiB

    normalize_rows<<<N_ROWS / 4, 256, 0, stream>>>(emb, An, N_ROWS);
    arcface_gemm<<<dim3(MTILES * NPANEL), 256, 0, stream>>>(An, wgt, labels, out);
}